// Round 1
// 257.625 us; speedup vs baseline: 1.0483x; 1.0483x over previous
//
#include <hip/hip_runtime.h>
#include <hip/hip_bf16.h>
#include <stdint.h>

// Problem constants (fixed by reference): B=2, BEV=128, Q=16384, C=256,
// H=8, L=1, P=4, D=32. spatial_shapes == [[128,128]] (hardcoded).
#define Q_TOT 32768        // B*Q rows
#define CC 256
#define GRID_W 128
#define GRID_H 128

typedef __attribute__((ext_vector_type(8))) short short8;   // 8 bf16 = 4 VGPRs
typedef __attribute__((ext_vector_type(4))) float floatx4;  // MFMA accumulator

// ---------- helpers ----------
__device__ __forceinline__ ushort f2bf(float f) {
    union { float f; uint32_t u; } v; v.f = f;
    uint32_t r = (v.u + 0x7fffu + ((v.u >> 16) & 1u)) >> 16;   // RNE
    return (ushort)r;
}
__device__ __forceinline__ float bf2f(ushort s) {
    union { uint32_t u; float f; } v; v.u = ((uint32_t)s) << 16;
    return v.f;
}
// unpack 2 bf16 packed in a uint32 -> 2 floats (2 bit-ops)
__device__ __forceinline__ void bf2x2(uint32_t u, float& lo, float& hi) {
    union { uint32_t u; float f; } a, b;
    a.u = u << 16; b.u = u & 0xffff0000u;
    lo = a.f; hi = b.f;
}
// async global->LDS, 16B per lane. LDS dest must be wave-uniform.
__device__ __forceinline__ void async_load16(const void* g, void* l) {
    __builtin_amdgcn_global_load_lds(
        reinterpret_cast<const __attribute__((address_space(1))) uint32_t*>(
            reinterpret_cast<uintptr_t>(g)),
        reinterpret_cast<__attribute__((address_space(3))) uint32_t*>(
            reinterpret_cast<uintptr_t>(l)),
        16, 0, 0);
}

// ---------- prep: qsum = bf16(query+query_pos), vbf = bf16(value) ----------
__global__ __launch_bounds__(256)
void prep_convert(const float* __restrict__ q, const float* __restrict__ qp,
                  const float* __restrict__ val,
                  ushort* __restrict__ qsum, ushort* __restrict__ vbf)
{
    const int total = (Q_TOT * CC) / 4;     // float4 units per tensor
    for (int idx = blockIdx.x * blockDim.x + threadIdx.x; idx < 2 * total;
         idx += gridDim.x * blockDim.x) {
        if (idx < total) {
            float4 a = ((const float4*)q)[idx];
            float4 b = ((const float4*)qp)[idx];
            ushort4 o;
            o.x = f2bf(a.x + b.x); o.y = f2bf(a.y + b.y);
            o.z = f2bf(a.z + b.z); o.w = f2bf(a.w + b.w);
            ((ushort4*)qsum)[idx] = o;
        } else {
            int j = idx - total;
            float4 a = ((const float4*)val)[j];
            ushort4 o;
            o.x = f2bf(a.x); o.y = f2bf(a.y); o.z = f2bf(a.z); o.w = f2bf(a.w);
            ((ushort4*)vbf)[j] = o;
        }
    }
}

// ---------- prep: transposed bf16 weights + combined bias ----------
__global__ __launch_bounds__(256)
void prep_weights(const float* __restrict__ Wv, const float* __restrict__ Wo,
                  const float* __restrict__ Woff, const float* __restrict__ Ww,
                  const float* __restrict__ boff, const float* __restrict__ bw,
                  ushort* __restrict__ WvT, ushort* __restrict__ WoT,
                  ushort* __restrict__ WowT, float* __restrict__ bias_ow)
{
    int idx = blockIdx.x * blockDim.x + threadIdx.x;
    if (idx < 65536) {
        int n = idx >> 8, k = idx & 255;
        WvT[idx] = f2bf(Wv[k * 256 + n]);
    } else if (idx < 131072) {
        int t = idx - 65536; int n = t >> 8, k = t & 255;
        WoT[t] = f2bf(Wo[k * 256 + n]);
    } else if (idx < 155648) {
        int t = idx - 131072; int n = t >> 8, k = t & 255;
        float v = (n < 64) ? Woff[k * 64 + n] : Ww[k * 32 + (n - 64)];
        WowT[t] = f2bf(v);
    } else if (idx < 155744) {
        int t = idx - 155648;
        bias_ow[t] = (t < 64) ? boff[t] : bw[t - 64];
    }
}

// ---------- bf16 MFMA GEMM: C[M,N] = A[M,K] @ Bt[N,K]^T + bias (+res) ----------
// 2-phase double-buffered pipeline: issue next K-tile's global_load_lds BEFORE
// computing the current one; ONE barrier per K-step (vmcnt drain happens after
// compute, so HBM latency hides under MFMA+ds_read). Grid is XCD-swizzled
// (requires nwg % 8 == 0) so blocks sharing an A-panel share an XCD L2.
template <int BM, int BN, int WAVE_M, int WAVE_N, bool OUT_BF16>
__global__ __launch_bounds__(256)
void gemm_bf16(const ushort* __restrict__ A, const ushort* __restrict__ Bt,
               const float* __restrict__ bias, const float* __restrict__ res,
               void* __restrict__ Cout, int M, int N, int K)
{
    constexpr int TM = BM / WAVE_M / 16;   // MFMA row-tiles per wave
    constexpr int TN = BN / WAVE_N / 16;   // MFMA col-tiles per wave
    __shared__ ushort As[2][BM * 32];
    __shared__ ushort Bs[2][BN * 32];

    const int tid = threadIdx.x;
    const int lane = tid & 63;
    const int wave = tid >> 6;
    const int wm = wave / WAVE_N;
    const int wn = wave % WAVE_N;
    const int quad = lane >> 4;
    const int m16 = lane & 15;
    const int lrow = lane >> 2;          // staging: row within a 16-row group
    const int lkk = (lane & 3) * 8;      // staging: k element offset

    // bijective XCD swizzle (nwg % 8 == 0): hw-consecutive blocks round-robin
    // XCDs; remap so each XCD gets a contiguous tile chunk (A-panel reuse in
    // its private L2).
    const int nwg = gridDim.x * gridDim.y;
    const int hw = blockIdx.y * gridDim.x + blockIdx.x;
    const int t = (hw & 7) * (nwg >> 3) + (hw >> 3);
    const int bx = t % gridDim.x;
    const int by = t / gridDim.x;

    const int row0 = by * BM;
    const int col0 = bx * BN;

    floatx4 acc[TM][TN] = {};

    auto stage = [&](int buf, int k0) {
        #pragma unroll
        for (int i = wave; i < BM / 16; i += 4) {
            const ushort* src = A + (size_t)(row0 + i * 16 + lrow) * K + (k0 + lkk);
            async_load16(src, &As[buf][i * 16 * 32]);
        }
        #pragma unroll
        for (int i = wave; i < BN / 16; i += 4) {
            const ushort* src = Bt + (size_t)(col0 + i * 16 + lrow) * K + (k0 + lkk);
            async_load16(src, &Bs[buf][i * 16 * 32]);
        }
    };

    // prologue: fill buffer 0
    stage(0, 0);
    __syncthreads();                      // vmcnt(0) + barrier: buf0 ready

    int cur = 0;
    for (int k0 = 0; k0 < K; k0 += 32) {
        if (k0 + 32 < K) stage(cur ^ 1, k0 + 32);   // prefetch next tile

        short8 af[TM], bfr[TN];
        #pragma unroll
        for (int i = 0; i < TM; ++i)
            af[i] = *(const short8*)&As[cur][(wm * TM * 16 + i * 16 + m16) * 32 + quad * 8];
        #pragma unroll
        for (int j = 0; j < TN; ++j)
            bfr[j] = *(const short8*)&Bs[cur][(wn * TN * 16 + j * 16 + m16) * 32 + quad * 8];
        #pragma unroll
        for (int i = 0; i < TM; ++i)
            #pragma unroll
            for (int j = 0; j < TN; ++j)
                acc[i][j] = __builtin_amdgcn_mfma_f32_16x16x32_bf16(
                    af[i], bfr[j], acc[i][j], 0, 0, 0);

        __syncthreads();                  // drains prefetch; next buf ready
        cur ^= 1;
    }

    // epilogue: C/D layout col = lane&15, row = quad*4 + reg
    #pragma unroll
    for (int i = 0; i < TM; ++i) {
        #pragma unroll
        for (int j = 0; j < TN; ++j) {
            const int gcol = col0 + wn * TN * 16 + j * 16 + m16;
            const float bb = bias[gcol];
            #pragma unroll
            for (int r = 0; r < 4; ++r) {
                const int grow = row0 + wm * TM * 16 + i * 16 + quad * 4 + r;
                float v = acc[i][j][r] + bb;
                if (res) v += res[(size_t)grow * N + gcol];
                if constexpr (OUT_BF16)
                    ((ushort*)Cout)[(size_t)grow * N + gcol] = f2bf(v);
                else
                    ((float*)Cout)[(size_t)grow * N + gcol] = v;
            }
        }
    }
}

// ---------- bilinear deformable sampling (bf16 in/out), vectorized ----------
// 256 threads handle 8 queries: thread = (ql = tid>>5, h = (tid>>2)&7, dg = tid&3).
// Each thread produces 8 channels (d = dg*8..dg*8+7) via 16B corner loads.
#define QB 8
__global__ __launch_bounds__(256)
void sample_kernel(const ushort* __restrict__ v2,   // (B,16384,256) bf16
                   const ushort* __restrict__ ow,   // (B*Q,96) bf16: off(64)|w(32)
                   const float* __restrict__ ref,   // (B*Q,2)
                   ushort* __restrict__ out)        // (B*Q,256) bf16
{
    const int tid = threadIdx.x;
    const int ql = tid >> 5;
    const int h  = (tid >> 2) & 7;
    const int dg = tid & 3;
    const int q = blockIdx.x * QB + ql;
    const int b = q >> 14;

    // offsets for this (q,h): 8 bf16 = 16B aligned
    const ushort* op = ow + (size_t)q * 96 + h * 8;
    const uint4 oraw = *(const uint4*)op;
    float offs[8];
    bf2x2(oraw.x, offs[0], offs[1]);
    bf2x2(oraw.y, offs[2], offs[3]);
    bf2x2(oraw.z, offs[4], offs[5]);
    bf2x2(oraw.w, offs[6], offs[7]);

    // attention logits: 4 bf16 = 8B
    const uint2 wraw = *(const uint2*)(ow + (size_t)q * 96 + 64 + h * 4);
    float w0, w1, w2, w3;
    bf2x2(wraw.x, w0, w1);
    bf2x2(wraw.y, w2, w3);
    float m = fmaxf(fmaxf(w0, w1), fmaxf(w2, w3));
    float e0 = __expf(w0 - m), e1 = __expf(w1 - m), e2 = __expf(w2 - m), e3 = __expf(w3 - m);
    float inv = 1.f / (e0 + e1 + e2 + e3);
    float aw[4] = {e0 * inv, e1 * inv, e2 * inv, e3 * inv};

    const float rx = ref[(size_t)q * 2 + 0];
    const float ry = ref[(size_t)q * 2 + 1];
    const ushort* vb = v2 + (size_t)b * 16384 * 256 + h * 32 + dg * 8;

    float acc[8] = {};
    #pragma unroll
    for (int p = 0; p < 4; ++p) {
        float x = rx * (float)GRID_W + offs[p * 2 + 0] - 0.5f;
        float y = ry * (float)GRID_H + offs[p * 2 + 1] - 0.5f;
        float x0f = floorf(x), y0f = floorf(y);
        float dx = x - x0f, dy = y - y0f;
        int x0 = (int)x0f, y0 = (int)y0f;
        int x1 = x0 + 1, y1 = y0 + 1;
        float vx0 = (x0 >= 0 && x0 < GRID_W) ? 1.f : 0.f;
        float vx1 = (x1 >= 0 && x1 < GRID_W) ? 1.f : 0.f;
        float vy0 = (y0 >= 0 && y0 < GRID_H) ? 1.f : 0.f;
        float vy1 = (y1 >= 0 && y1 < GRID_H) ? 1.f : 0.f;
        int xc0 = min(max(x0, 0), GRID_W - 1), xc1 = min(max(x1, 0), GRID_W - 1);
        int yc0 = min(max(y0, 0), GRID_H - 1), yc1 = min(max(y1, 0), GRID_H - 1);
        float cw00 = aw[p] * (1.f - dx) * (1.f - dy) * vx0 * vy0;
        float cw10 = aw[p] * dx * (1.f - dy) * vx1 * vy0;
        float cw01 = aw[p] * (1.f - dx) * dy * vx0 * vy1;
        float cw11 = aw[p] * dx * dy * vx1 * vy1;
        const int base0 = yc0 * GRID_W, base1 = yc1 * GRID_W;
        const uint4 r00 = *(const uint4*)(vb + (size_t)(base0 + xc0) * 256);
        const uint4 r10 = *(const uint4*)(vb + (size_t)(base0 + xc1) * 256);
        const uint4 r01 = *(const uint4*)(vb + (size_t)(base1 + xc0) * 256);
        const uint4 r11 = *(const uint4*)(vb + (size_t)(base1 + xc1) * 256);
        float lo, hi;
        bf2x2(r00.x, lo, hi); acc[0] += cw00 * lo; acc[1] += cw00 * hi;
        bf2x2(r00.y, lo, hi); acc[2] += cw00 * lo; acc[3] += cw00 * hi;
        bf2x2(r00.z, lo, hi); acc[4] += cw00 * lo; acc[5] += cw00 * hi;
        bf2x2(r00.w, lo, hi); acc[6] += cw00 * lo; acc[7] += cw00 * hi;
        bf2x2(r10.x, lo, hi); acc[0] += cw10 * lo; acc[1] += cw10 * hi;
        bf2x2(r10.y, lo, hi); acc[2] += cw10 * lo; acc[3] += cw10 * hi;
        bf2x2(r10.z, lo, hi); acc[4] += cw10 * lo; acc[5] += cw10 * hi;
        bf2x2(r10.w, lo, hi); acc[6] += cw10 * lo; acc[7] += cw10 * hi;
        bf2x2(r01.x, lo, hi); acc[0] += cw01 * lo; acc[1] += cw01 * hi;
        bf2x2(r01.y, lo, hi); acc[2] += cw01 * lo; acc[3] += cw01 * hi;
        bf2x2(r01.z, lo, hi); acc[4] += cw01 * lo; acc[5] += cw01 * hi;
        bf2x2(r01.w, lo, hi); acc[6] += cw01 * lo; acc[7] += cw01 * hi;
        bf2x2(r11.x, lo, hi); acc[0] += cw11 * lo; acc[1] += cw11 * hi;
        bf2x2(r11.y, lo, hi); acc[2] += cw11 * lo; acc[3] += cw11 * hi;
        bf2x2(r11.z, lo, hi); acc[4] += cw11 * lo; acc[5] += cw11 * hi;
        bf2x2(r11.w, lo, hi); acc[6] += cw11 * lo; acc[7] += cw11 * hi;
    }

    // pack 8 channels -> 16B store
    uint4 o;
    o.x = ((uint32_t)f2bf(acc[1]) << 16) | f2bf(acc[0]);
    o.y = ((uint32_t)f2bf(acc[3]) << 16) | f2bf(acc[2]);
    o.z = ((uint32_t)f2bf(acc[5]) << 16) | f2bf(acc[4]);
    o.w = ((uint32_t)f2bf(acc[7]) << 16) | f2bf(acc[6]);
    *(uint4*)(out + (size_t)q * 256 + h * 32 + dg * 8) = o;
}

extern "C" void kernel_launch(void* const* d_in, const int* in_sizes, int n_in,
                              void* d_out, int out_size, void* d_ws, size_t ws_size,
                              hipStream_t stream) {
    const float* query     = (const float*)d_in[0];
    const float* value     = (const float*)d_in[1];
    const float* identity  = (const float*)d_in[2];
    const float* query_pos = (const float*)d_in[3];
    const float* refpts    = (const float*)d_in[4];
    const float* Wv   = (const float*)d_in[7];
    const float* bv   = (const float*)d_in[8];
    const float* Woff = (const float*)d_in[9];
    const float* boff = (const float*)d_in[10];
    const float* Ww   = (const float*)d_in[11];
    const float* bw   = (const float*)d_in[12];
    const float* Wo   = (const float*)d_in[13];
    const float* bo   = (const float*)d_in[14];
    float* out = (float*)d_out;

    char* ws = (char*)d_ws;
    ushort* qsum_bf  = (ushort*)(ws);                      // 16,777,216 B
    ushort* value_bf = (ushort*)(ws + 16777216);           // 16,777,216 B
    ushort* v2_bf    = (ushort*)(ws + 33554432);           // 16,777,216 B
    ushort* ow_bf    = (ushort*)(ws + 50331648);           //  6,291,456 B
    ushort* samp_bf  = (ushort*)(ws + 56623104);           // 16,777,216 B
    ushort* WvT      = (ushort*)(ws + 73400320);           //    131,072 B
    ushort* WoT      = (ushort*)(ws + 73531392);           //    131,072 B
    ushort* WowT     = (ushort*)(ws + 73662464);           //     49,152 B
    float*  bias_ow  = (float*)(ws + 73711616);            //        384 B

    // 1) bf16 conversions of activations
    prep_convert<<<8192, 256, 0, stream>>>(query, query_pos, value, qsum_bf, value_bf);
    // 2) transposed bf16 weights + combined bias
    prep_weights<<<609, 256, 0, stream>>>(Wv, Wo, Woff, Ww, boff, bw,
                                          WvT, WoT, WowT, bias_ow);
    // 3) v2 = value @ Wv + bv  (bf16 out)  — 1024 blocks, XCD-swizzled
    gemm_bf16<128, 64, 2, 2, true><<<dim3(4, 256), 256, 0, stream>>>(
        value_bf, WvT, bv, nullptr, v2_bf, Q_TOT, 256, 256);
    // 4) ow = qsum @ [Woff|Ww] + [boff|bw]  (bf16 out, N=96) — 1024 blocks
    gemm_bf16<32, 96, 2, 2, true><<<dim3(1, 1024), 256, 0, stream>>>(
        qsum_bf, WowT, bias_ow, nullptr, ow_bf, Q_TOT, 96, 256);
    // 5) deformable bilinear sampling -> samp (bf16)
    sample_kernel<<<dim3(Q_TOT / QB), 256, 0, stream>>>(v2_bf, ow_bf, refpts, samp_bf);
    // 6) out = samp @ Wo + bo + identity  (fp32 out) — 1024 blocks, XCD-swizzled
    gemm_bf16<128, 64, 2, 2, false><<<dim3(4, 256), 256, 0, stream>>>(
        samp_bf, WoT, bo, identity, out, Q_TOT, 256, 256);
}

// Round 2
// 253.898 us; speedup vs baseline: 1.0637x; 1.0147x over previous
//
#include <hip/hip_runtime.h>
#include <hip/hip_bf16.h>
#include <stdint.h>

// Problem constants (fixed by reference): B=2, BEV=128, Q=16384, C=256,
// H=8, L=1, P=4, D=32. spatial_shapes == [[128,128]] (hardcoded).
#define Q_TOT 32768        // B*Q rows
#define CC 256
#define GRID_W 128
#define GRID_H 128

typedef __attribute__((ext_vector_type(8))) short short8;   // 8 bf16 = 4 VGPRs
typedef __attribute__((ext_vector_type(4))) float floatx4;  // MFMA accumulator

// ---------- helpers ----------
__device__ __forceinline__ ushort f2bf(float f) {
    union { float f; uint32_t u; } v; v.f = f;
    uint32_t r = (v.u + 0x7fffu + ((v.u >> 16) & 1u)) >> 16;   // RNE
    return (ushort)r;
}
// unpack 2 bf16 packed in a uint32 -> 2 floats (2 bit-ops)
__device__ __forceinline__ void bf2x2(uint32_t u, float& lo, float& hi) {
    union { uint32_t u; float f; } a, b;
    a.u = u << 16; b.u = u & 0xffff0000u;
    lo = a.f; hi = b.f;
}
// async global->LDS, 16B per lane. LDS dest must be wave-uniform.
__device__ __forceinline__ void async_load16(const void* g, void* l) {
    __builtin_amdgcn_global_load_lds(
        reinterpret_cast<const __attribute__((address_space(1))) uint32_t*>(
            reinterpret_cast<uintptr_t>(g)),
        reinterpret_cast<__attribute__((address_space(3))) uint32_t*>(
            reinterpret_cast<uintptr_t>(l)),
        16, 0, 0);
}

// ---------- prep: transposed bf16 weights + combined bias ----------
__global__ __launch_bounds__(256)
void prep_weights(const float* __restrict__ Wv, const float* __restrict__ Wo,
                  const float* __restrict__ Woff, const float* __restrict__ Ww,
                  const float* __restrict__ boff, const float* __restrict__ bw,
                  ushort* __restrict__ WvT, ushort* __restrict__ WoT,
                  ushort* __restrict__ WowT, float* __restrict__ bias_ow)
{
    int idx = blockIdx.x * blockDim.x + threadIdx.x;
    if (idx < 65536) {
        int n = idx >> 8, k = idx & 255;
        WvT[idx] = f2bf(Wv[k * 256 + n]);
    } else if (idx < 131072) {
        int t = idx - 65536; int n = t >> 8, k = t & 255;
        WoT[t] = f2bf(Wo[k * 256 + n]);
    } else if (idx < 155648) {
        int t = idx - 131072; int n = t >> 8, k = t & 255;
        float v = (n < 64) ? Woff[k * 64 + n] : Ww[k * 32 + (n - 64)];
        WowT[t] = f2bf(v);
    } else if (idx < 155744) {
        int t = idx - 155648;
        bias_ow[t] = (t < 64) ? boff[t] : bw[t - 64];
    }
}

// ---------- bf16 MFMA GEMM: C[M,N] = A[M,K] @ Bt[N,K]^T + bias (+res) ----------
// 2-phase double-buffered pipeline; one barrier per K-step. XCD-swizzled grid
// (requires nwg % 8 == 0) so blocks sharing an A-panel share an XCD L2.
// CONV = 0: A is bf16, staged via global_load_lds (async).
// CONV = 1: A is fp32, reg-staged with in-register bf16 conversion.
// CONV = 2: A is fp32 pair (Av + A2), summed then converted (fuses q+query_pos).
template <int BM, int BN, int WAVE_M, int WAVE_N, bool OUT_BF16, int CONV>
__global__ __launch_bounds__(256)
void gemm_bf16(const void* __restrict__ Av, const float* __restrict__ A2,
               const ushort* __restrict__ Bt,
               const float* __restrict__ bias, const float* __restrict__ res,
               void* __restrict__ Cout, int M, int N, int K)
{
    constexpr int TM = BM / WAVE_M / 16;   // MFMA row-tiles per wave
    constexpr int TN = BN / WAVE_N / 16;   // MFMA col-tiles per wave
    __shared__ __align__(16) ushort As[2][BM * 32];
    __shared__ __align__(16) ushort Bs[2][BN * 32];

    const int tid = threadIdx.x;
    const int lane = tid & 63;
    const int wave = tid >> 6;
    const int wm = wave / WAVE_N;
    const int wn = wave % WAVE_N;
    const int quad = lane >> 4;
    const int m16 = lane & 15;
    const int lrow = lane >> 2;          // staging: row within a 16-row group
    const int lkk = (lane & 3) * 8;      // staging: k element offset

    // bijective XCD swizzle (nwg % 8 == 0): remap so each XCD gets a
    // contiguous chunk of tiles (A-panel reuse in its private L2).
    const int nwg = gridDim.x * gridDim.y;
    const int hw = blockIdx.y * gridDim.x + blockIdx.x;
    const int t = (hw & 7) * (nwg >> 3) + (hw >> 3);
    const int bx = t % gridDim.x;
    const int by = t / gridDim.x;

    const int row0 = by * BM;
    const int col0 = bx * BN;

    floatx4 acc[TM][TN] = {};

    auto stage = [&](int buf, int k0) {
        #pragma unroll
        for (int i = wave; i < BM / 16; i += 4) {
            const int r = row0 + i * 16 + lrow;
            if constexpr (CONV == 0) {
                const ushort* src = (const ushort*)Av + (size_t)r * K + (k0 + lkk);
                async_load16(src, &As[buf][i * 16 * 32]);
            } else {
                const float* src = (const float*)Av + (size_t)r * K + (k0 + lkk);
                float4 a0 = ((const float4*)src)[0];
                float4 a1 = ((const float4*)src)[1];
                if constexpr (CONV == 2) {
                    const float* s2 = A2 + (size_t)r * K + (k0 + lkk);
                    float4 b0 = ((const float4*)s2)[0];
                    float4 b1 = ((const float4*)s2)[1];
                    a0.x += b0.x; a0.y += b0.y; a0.z += b0.z; a0.w += b0.w;
                    a1.x += b1.x; a1.y += b1.y; a1.z += b1.z; a1.w += b1.w;
                }
                uint4 o;
                o.x = ((uint32_t)f2bf(a0.y) << 16) | f2bf(a0.x);
                o.y = ((uint32_t)f2bf(a0.w) << 16) | f2bf(a0.z);
                o.z = ((uint32_t)f2bf(a1.y) << 16) | f2bf(a1.x);
                o.w = ((uint32_t)f2bf(a1.w) << 16) | f2bf(a1.z);
                *(uint4*)&As[buf][i * 16 * 32 + lrow * 32 + lkk] = o;
            }
        }
        #pragma unroll
        for (int i = wave; i < BN / 16; i += 4) {
            const ushort* src = Bt + (size_t)(col0 + i * 16 + lrow) * K + (k0 + lkk);
            async_load16(src, &Bs[buf][i * 16 * 32]);
        }
    };

    // prologue: fill buffer 0
    stage(0, 0);
    __syncthreads();                      // drain: buf0 ready

    int cur = 0;
    for (int k0 = 0; k0 < K; k0 += 32) {
        if (k0 + 32 < K) stage(cur ^ 1, k0 + 32);   // prefetch next tile

        short8 af[TM], bfr[TN];
        #pragma unroll
        for (int i = 0; i < TM; ++i)
            af[i] = *(const short8*)&As[cur][(wm * TM * 16 + i * 16 + m16) * 32 + quad * 8];
        #pragma unroll
        for (int j = 0; j < TN; ++j)
            bfr[j] = *(const short8*)&Bs[cur][(wn * TN * 16 + j * 16 + m16) * 32 + quad * 8];
        #pragma unroll
        for (int i = 0; i < TM; ++i)
            #pragma unroll
            for (int j = 0; j < TN; ++j)
                acc[i][j] = __builtin_amdgcn_mfma_f32_16x16x32_bf16(
                    af[i], bfr[j], acc[i][j], 0, 0, 0);

        __syncthreads();                  // drains prefetch; next buf ready
        cur ^= 1;
    }

    // epilogue: C/D layout col = lane&15, row = quad*4 + reg
    #pragma unroll
    for (int i = 0; i < TM; ++i) {
        #pragma unroll
        for (int j = 0; j < TN; ++j) {
            const int gcol = col0 + wn * TN * 16 + j * 16 + m16;
            const float bb = bias[gcol];
            #pragma unroll
            for (int r = 0; r < 4; ++r) {
                const int grow = row0 + wm * TM * 16 + i * 16 + quad * 4 + r;
                float v = acc[i][j][r] + bb;
                if (res) v += res[(size_t)grow * N + gcol];
                if constexpr (OUT_BF16)
                    ((ushort*)Cout)[(size_t)grow * N + gcol] = f2bf(v);
                else
                    ((float*)Cout)[(size_t)grow * N + gcol] = v;
            }
        }
    }
}

// ---------- bilinear deformable sampling (bf16 in/out), vectorized ----------
// 256 threads handle 8 queries: thread = (ql = tid>>5, h = (tid>>2)&7, dg = tid&3).
// Each thread produces 8 channels (d = dg*8..dg*8+7) via 16B corner loads.
#define QB 8
__global__ __launch_bounds__(256)
void sample_kernel(const ushort* __restrict__ v2,   // (B,16384,256) bf16
                   const ushort* __restrict__ ow,   // (B*Q,96) bf16: off(64)|w(32)
                   const float* __restrict__ ref,   // (B*Q,2)
                   ushort* __restrict__ out)        // (B*Q,256) bf16
{
    const int tid = threadIdx.x;
    const int ql = tid >> 5;
    const int h  = (tid >> 2) & 7;
    const int dg = tid & 3;
    const int q = blockIdx.x * QB + ql;
    const int b = q >> 14;

    // offsets for this (q,h): 8 bf16 = 16B aligned
    const ushort* op = ow + (size_t)q * 96 + h * 8;
    const uint4 oraw = *(const uint4*)op;
    float offs[8];
    bf2x2(oraw.x, offs[0], offs[1]);
    bf2x2(oraw.y, offs[2], offs[3]);
    bf2x2(oraw.z, offs[4], offs[5]);
    bf2x2(oraw.w, offs[6], offs[7]);

    // attention logits: 4 bf16 = 8B
    const uint2 wraw = *(const uint2*)(ow + (size_t)q * 96 + 64 + h * 4);
    float w0, w1, w2, w3;
    bf2x2(wraw.x, w0, w1);
    bf2x2(wraw.y, w2, w3);
    float m = fmaxf(fmaxf(w0, w1), fmaxf(w2, w3));
    float e0 = __expf(w0 - m), e1 = __expf(w1 - m), e2 = __expf(w2 - m), e3 = __expf(w3 - m);
    float inv = 1.f / (e0 + e1 + e2 + e3);
    float aw[4] = {e0 * inv, e1 * inv, e2 * inv, e3 * inv};

    const float rx = ref[(size_t)q * 2 + 0];
    const float ry = ref[(size_t)q * 2 + 1];
    const ushort* vb = v2 + (size_t)b * 16384 * 256 + h * 32 + dg * 8;

    float acc[8] = {};
    #pragma unroll
    for (int p = 0; p < 4; ++p) {
        float x = rx * (float)GRID_W + offs[p * 2 + 0] - 0.5f;
        float y = ry * (float)GRID_H + offs[p * 2 + 1] - 0.5f;
        float x0f = floorf(x), y0f = floorf(y);
        float dx = x - x0f, dy = y - y0f;
        int x0 = (int)x0f, y0 = (int)y0f;
        int x1 = x0 + 1, y1 = y0 + 1;
        float vx0 = (x0 >= 0 && x0 < GRID_W) ? 1.f : 0.f;
        float vx1 = (x1 >= 0 && x1 < GRID_W) ? 1.f : 0.f;
        float vy0 = (y0 >= 0 && y0 < GRID_H) ? 1.f : 0.f;
        float vy1 = (y1 >= 0 && y1 < GRID_H) ? 1.f : 0.f;
        int xc0 = min(max(x0, 0), GRID_W - 1), xc1 = min(max(x1, 0), GRID_W - 1);
        int yc0 = min(max(y0, 0), GRID_H - 1), yc1 = min(max(y1, 0), GRID_H - 1);
        float cw00 = aw[p] * (1.f - dx) * (1.f - dy) * vx0 * vy0;
        float cw10 = aw[p] * dx * (1.f - dy) * vx1 * vy0;
        float cw01 = aw[p] * (1.f - dx) * dy * vx0 * vy1;
        float cw11 = aw[p] * dx * dy * vx1 * vy1;
        const int base0 = yc0 * GRID_W, base1 = yc1 * GRID_W;
        const uint4 r00 = *(const uint4*)(vb + (size_t)(base0 + xc0) * 256);
        const uint4 r10 = *(const uint4*)(vb + (size_t)(base0 + xc1) * 256);
        const uint4 r01 = *(const uint4*)(vb + (size_t)(base1 + xc0) * 256);
        const uint4 r11 = *(const uint4*)(vb + (size_t)(base1 + xc1) * 256);
        float lo, hi;
        bf2x2(r00.x, lo, hi); acc[0] += cw00 * lo; acc[1] += cw00 * hi;
        bf2x2(r00.y, lo, hi); acc[2] += cw00 * lo; acc[3] += cw00 * hi;
        bf2x2(r00.z, lo, hi); acc[4] += cw00 * lo; acc[5] += cw00 * hi;
        bf2x2(r00.w, lo, hi); acc[6] += cw00 * lo; acc[7] += cw00 * hi;
        bf2x2(r10.x, lo, hi); acc[0] += cw10 * lo; acc[1] += cw10 * hi;
        bf2x2(r10.y, lo, hi); acc[2] += cw10 * lo; acc[3] += cw10 * hi;
        bf2x2(r10.z, lo, hi); acc[4] += cw10 * lo; acc[5] += cw10 * hi;
        bf2x2(r10.w, lo, hi); acc[6] += cw10 * lo; acc[7] += cw10 * hi;
        bf2x2(r01.x, lo, hi); acc[0] += cw01 * lo; acc[1] += cw01 * hi;
        bf2x2(r01.y, lo, hi); acc[2] += cw01 * lo; acc[3] += cw01 * hi;
        bf2x2(r01.z, lo, hi); acc[4] += cw01 * lo; acc[5] += cw01 * hi;
        bf2x2(r01.w, lo, hi); acc[6] += cw01 * lo; acc[7] += cw01 * hi;
        bf2x2(r11.x, lo, hi); acc[0] += cw11 * lo; acc[1] += cw11 * hi;
        bf2x2(r11.y, lo, hi); acc[2] += cw11 * lo; acc[3] += cw11 * hi;
        bf2x2(r11.z, lo, hi); acc[4] += cw11 * lo; acc[5] += cw11 * hi;
        bf2x2(r11.w, lo, hi); acc[6] += cw11 * lo; acc[7] += cw11 * hi;
    }

    // pack 8 channels -> 16B store
    uint4 o;
    o.x = ((uint32_t)f2bf(acc[1]) << 16) | f2bf(acc[0]);
    o.y = ((uint32_t)f2bf(acc[3]) << 16) | f2bf(acc[2]);
    o.z = ((uint32_t)f2bf(acc[5]) << 16) | f2bf(acc[4]);
    o.w = ((uint32_t)f2bf(acc[7]) << 16) | f2bf(acc[6]);
    *(uint4*)(out + (size_t)q * 256 + h * 32 + dg * 8) = o;
}

extern "C" void kernel_launch(void* const* d_in, const int* in_sizes, int n_in,
                              void* d_out, int out_size, void* d_ws, size_t ws_size,
                              hipStream_t stream) {
    const float* query     = (const float*)d_in[0];
    const float* value     = (const float*)d_in[1];
    const float* identity  = (const float*)d_in[2];
    const float* query_pos = (const float*)d_in[3];
    const float* refpts    = (const float*)d_in[4];
    const float* Wv   = (const float*)d_in[7];
    const float* bv   = (const float*)d_in[8];
    const float* Woff = (const float*)d_in[9];
    const float* boff = (const float*)d_in[10];
    const float* Ww   = (const float*)d_in[11];
    const float* bw   = (const float*)d_in[12];
    const float* Wo   = (const float*)d_in[13];
    const float* bo   = (const float*)d_in[14];
    float* out = (float*)d_out;

    char* ws = (char*)d_ws;
    ushort* v2_bf    = (ushort*)(ws);                      // 16,777,216 B
    ushort* ow_bf    = (ushort*)(ws + 16777216);           //  6,291,456 B
    ushort* samp_bf  = (ushort*)(ws + 23068672);           // 16,777,216 B
    ushort* WvT      = (ushort*)(ws + 39845888);           //    131,072 B
    ushort* WoT      = (ushort*)(ws + 39976960);           //    131,072 B
    ushort* WowT     = (ushort*)(ws + 40108032);           //     49,152 B
    float*  bias_ow  = (float*)(ws + 40157184);            //        384 B

    // 1) transposed bf16 weights + combined bias
    prep_weights<<<609, 256, 0, stream>>>(Wv, Wo, Woff, Ww, boff, bw,
                                          WvT, WoT, WowT, bias_ow);
    // 2) v2 = value @ Wv + bv  (fp32 A converted in staging, bf16 out)
    gemm_bf16<128, 64, 2, 2, true, 1><<<dim3(4, 256), 256, 0, stream>>>(
        value, nullptr, WvT, bv, nullptr, v2_bf, Q_TOT, 256, 256);
    // 3) ow = (query+query_pos) @ [Woff|Ww] + [boff|bw]  (fused add+convert, N=96)
    gemm_bf16<32, 96, 2, 2, true, 2><<<dim3(1, 1024), 256, 0, stream>>>(
        query, query_pos, WowT, bias_ow, nullptr, ow_bf, Q_TOT, 96, 256);
    // 4) deformable bilinear sampling -> samp (bf16)
    sample_kernel<<<dim3(Q_TOT / QB), 256, 0, stream>>>(v2_bf, ow_bf, refpts, samp_bf);
    // 5) out = samp @ Wo + bo + identity  (fp32 out)
    gemm_bf16<128, 64, 2, 2, false, 0><<<dim3(4, 256), 256, 0, stream>>>(
        samp_bf, nullptr, WoT, bo, identity, out, Q_TOT, 256, 256);
}

// Round 3
// 230.459 us; speedup vs baseline: 1.1719x; 1.1017x over previous
//
#include <hip/hip_runtime.h>
#include <hip/hip_bf16.h>
#include <stdint.h>

// Problem constants (fixed by reference): B=2, BEV=128, Q=16384, C=256,
// H=8, L=1, P=4, D=32. spatial_shapes == [[128,128]] (hardcoded).
#define Q_TOT 32768        // B*Q rows
#define CC 256
#define GRID_W 128
#define GRID_H 128

typedef __attribute__((ext_vector_type(8))) short short8;   // 8 bf16 = 4 VGPRs
typedef __attribute__((ext_vector_type(4))) float floatx4;  // MFMA accumulator

// ---------- helpers ----------
__device__ __forceinline__ ushort f2bf(float f) {
    union { float f; uint32_t u; } v; v.f = f;
    uint32_t r = (v.u + 0x7fffu + ((v.u >> 16) & 1u)) >> 16;   // RNE
    return (ushort)r;
}
// unpack 2 bf16 packed in a uint32 -> 2 floats (2 bit-ops)
__device__ __forceinline__ void bf2x2(uint32_t u, float& lo, float& hi) {
    union { uint32_t u; float f; } a, b;
    a.u = u << 16; b.u = u & 0xffff0000u;
    lo = a.f; hi = b.f;
}
// async global->LDS, 16B per lane. LDS dest must be wave-uniform.
__device__ __forceinline__ void async_load16(const void* g, void* l) {
    __builtin_amdgcn_global_load_lds(
        reinterpret_cast<const __attribute__((address_space(1))) uint32_t*>(
            reinterpret_cast<uintptr_t>(g)),
        reinterpret_cast<__attribute__((address_space(3))) uint32_t*>(
            reinterpret_cast<uintptr_t>(l)),
        16, 0, 0);
}

// ---------- prep: transposed bf16 weights ----------
__global__ __launch_bounds__(256)
void prep_weights(const float* __restrict__ Wv, const float* __restrict__ Wo,
                  const float* __restrict__ Woff, const float* __restrict__ Ww,
                  ushort* __restrict__ WvT, ushort* __restrict__ WoT,
                  ushort* __restrict__ WowT)
{
    int idx = blockIdx.x * blockDim.x + threadIdx.x;
    if (idx < 65536) {
        int n = idx >> 8, k = idx & 255;
        WvT[idx] = f2bf(Wv[k * 256 + n]);
    } else if (idx < 131072) {
        int t = idx - 65536; int n = t >> 8, k = t & 255;
        WoT[t] = f2bf(Wo[k * 256 + n]);
    } else if (idx < 155648) {
        int t = idx - 131072; int n = t >> 8, k = t & 255;
        float v = (n < 64) ? Woff[k * 64 + n] : Ww[k * 32 + (n - 64)];
        WowT[t] = f2bf(v);
    }
}

// ---------- bf16 MFMA GEMM: C[M,N] = A[M,K] @ Bt[N,K]^T + bias (+res) ----------
// 2-phase double-buffered pipeline; one barrier per K-step. XCD-swizzled grid
// (requires nwg % 8 == 0). CONV=1: A is fp32, reg-staged with bf16 conversion.
template <int BM, int BN, int WAVE_M, int WAVE_N, bool OUT_BF16, int CONV>
__global__ __launch_bounds__(256)
void gemm_bf16(const void* __restrict__ Av, const float* __restrict__ A2,
               const ushort* __restrict__ Bt,
               const float* __restrict__ bias, const float* __restrict__ res,
               void* __restrict__ Cout, int M, int N, int K)
{
    constexpr int TM = BM / WAVE_M / 16;   // MFMA row-tiles per wave
    constexpr int TN = BN / WAVE_N / 16;   // MFMA col-tiles per wave
    __shared__ __align__(16) ushort As[2][BM * 32];
    __shared__ __align__(16) ushort Bs[2][BN * 32];

    const int tid = threadIdx.x;
    const int lane = tid & 63;
    const int wave = tid >> 6;
    const int wm = wave / WAVE_N;
    const int wn = wave % WAVE_N;
    const int quad = lane >> 4;
    const int m16 = lane & 15;
    const int lrow = lane >> 2;          // staging: row within a 16-row group
    const int lkk = (lane & 3) * 8;      // staging: k element offset

    const int nwg = gridDim.x * gridDim.y;
    const int hw = blockIdx.y * gridDim.x + blockIdx.x;
    const int t = (hw & 7) * (nwg >> 3) + (hw >> 3);
    const int bx = t % gridDim.x;
    const int by = t / gridDim.x;

    const int row0 = by * BM;
    const int col0 = bx * BN;

    floatx4 acc[TM][TN] = {};

    auto stage = [&](int buf, int k0) {
        #pragma unroll
        for (int i = wave; i < BM / 16; i += 4) {
            const int r = row0 + i * 16 + lrow;
            if constexpr (CONV == 0) {
                const ushort* src = (const ushort*)Av + (size_t)r * K + (k0 + lkk);
                async_load16(src, &As[buf][i * 16 * 32]);
            } else {
                const float* src = (const float*)Av + (size_t)r * K + (k0 + lkk);
                float4 a0 = ((const float4*)src)[0];
                float4 a1 = ((const float4*)src)[1];
                if constexpr (CONV == 2) {
                    const float* s2 = A2 + (size_t)r * K + (k0 + lkk);
                    float4 b0 = ((const float4*)s2)[0];
                    float4 b1 = ((const float4*)s2)[1];
                    a0.x += b0.x; a0.y += b0.y; a0.z += b0.z; a0.w += b0.w;
                    a1.x += b1.x; a1.y += b1.y; a1.z += b1.z; a1.w += b1.w;
                }
                uint4 o;
                o.x = ((uint32_t)f2bf(a0.y) << 16) | f2bf(a0.x);
                o.y = ((uint32_t)f2bf(a0.w) << 16) | f2bf(a0.z);
                o.z = ((uint32_t)f2bf(a1.y) << 16) | f2bf(a1.x);
                o.w = ((uint32_t)f2bf(a1.w) << 16) | f2bf(a1.z);
                *(uint4*)&As[buf][i * 16 * 32 + lrow * 32 + lkk] = o;
            }
        }
        #pragma unroll
        for (int i = wave; i < BN / 16; i += 4) {
            const ushort* src = Bt + (size_t)(col0 + i * 16 + lrow) * K + (k0 + lkk);
            async_load16(src, &Bs[buf][i * 16 * 32]);
        }
    };

    stage(0, 0);
    __syncthreads();

    int cur = 0;
    for (int k0 = 0; k0 < K; k0 += 32) {
        if (k0 + 32 < K) stage(cur ^ 1, k0 + 32);

        short8 af[TM], bfr[TN];
        #pragma unroll
        for (int i = 0; i < TM; ++i)
            af[i] = *(const short8*)&As[cur][(wm * TM * 16 + i * 16 + m16) * 32 + quad * 8];
        #pragma unroll
        for (int j = 0; j < TN; ++j)
            bfr[j] = *(const short8*)&Bs[cur][(wn * TN * 16 + j * 16 + m16) * 32 + quad * 8];
        #pragma unroll
        for (int i = 0; i < TM; ++i)
            #pragma unroll
            for (int j = 0; j < TN; ++j)
                acc[i][j] = __builtin_amdgcn_mfma_f32_16x16x32_bf16(
                    af[i], bfr[j], acc[i][j], 0, 0, 0);

        __syncthreads();
        cur ^= 1;
    }

    #pragma unroll
    for (int i = 0; i < TM; ++i) {
        #pragma unroll
        for (int j = 0; j < TN; ++j) {
            const int gcol = col0 + wn * TN * 16 + j * 16 + m16;
            const float bb = bias[gcol];
            #pragma unroll
            for (int r = 0; r < 4; ++r) {
                const int grow = row0 + wm * TM * 16 + i * 16 + quad * 4 + r;
                float v = acc[i][j][r] + bb;
                if (res) v += res[(size_t)grow * N + gcol];
                if constexpr (OUT_BF16)
                    ((ushort*)Cout)[(size_t)grow * N + gcol] = f2bf(v);
                else
                    ((float*)Cout)[(size_t)grow * N + gcol] = v;
            }
        }
    }
}

// ---------- fused: ow-GEMM -> sampling -> out-GEMM, one block = 64 queries ----
// Phase 1: ow[64x96] = (query+qpos)[64x256] @ WowT^T + bias   (LDS f32)
// Phase 2: softmax + bilinear gather from v2 -> samp[64x256] bf16 (LDS, padded)
// Phase 3: out[64x256] = samp @ WoT^T + bo + identity          (fp32 global)
// LDS: phase1/2 region (As 4K | Bsow 6K | owl 26.6K) aliased by phase-3 Wo
// double-buffer (32K); samp (34K, row stride 272 ushorts for bank spread).
#define FBM 64
__global__ __launch_bounds__(256)
void fused_attn(const float* __restrict__ query, const float* __restrict__ qpos,
                const ushort* __restrict__ WowT,   // [96][256] bf16
                const float* __restrict__ boff, const float* __restrict__ bw,
                const ushort* __restrict__ v2,     // (B,16384,256) bf16
                const float* __restrict__ ref,     // (B*Q,2)
                const ushort* __restrict__ WoT,    // [256][256] bf16
                const float* __restrict__ bo, const float* __restrict__ identity,
                float* __restrict__ out)
{
    __shared__ __align__(16) char smem[71680];
    ushort* As   = (ushort*)smem;             // [64][32] bf16      (phase 1)
    ushort* Bsow = (ushort*)(smem + 4096);    // [96][32] bf16      (phase 1)
    float*  owl  = (float*)(smem + 10240);    // [64][104] f32      (phase 1->2)
    ushort* samp = (ushort*)(smem + 36864);   // [64][272] bf16     (phase 2->3)
    ushort* Bwo  = (ushort*)smem;             // [2][256][32] bf16  (phase 3, aliased)

    const int tid = threadIdx.x;
    const int lane = tid & 63;
    const int wave = tid >> 6;
    const int quad = lane >> 4;
    const int m16 = lane & 15;
    const int lrow = lane >> 2;
    const int lkk = (lane & 3) * 8;
    const int wm = wave >> 1;     // 0..1
    const int wn = wave & 1;      // 0..1

    const int q0 = blockIdx.x * FBM;

    // ---------------- phase 1: ow GEMM (single-buffered, K=256) ----------------
    floatx4 aow[2][3] = {};
    for (int k0 = 0; k0 < 256; k0 += 32) {
        {   // reg-stage A: fuse query+query_pos, convert to bf16
            const int r = wave * 16 + lrow;
            const float* s1 = query + (size_t)(q0 + r) * 256 + (k0 + lkk);
            const float* s2 = qpos  + (size_t)(q0 + r) * 256 + (k0 + lkk);
            float4 a0 = ((const float4*)s1)[0];
            float4 a1 = ((const float4*)s1)[1];
            float4 b0 = ((const float4*)s2)[0];
            float4 b1 = ((const float4*)s2)[1];
            a0.x += b0.x; a0.y += b0.y; a0.z += b0.z; a0.w += b0.w;
            a1.x += b1.x; a1.y += b1.y; a1.z += b1.z; a1.w += b1.w;
            uint4 o;
            o.x = ((uint32_t)f2bf(a0.y) << 16) | f2bf(a0.x);
            o.y = ((uint32_t)f2bf(a0.w) << 16) | f2bf(a0.z);
            o.z = ((uint32_t)f2bf(a1.y) << 16) | f2bf(a1.x);
            o.w = ((uint32_t)f2bf(a1.w) << 16) | f2bf(a1.z);
            *(uint4*)&As[r * 32 + lkk] = o;
        }
        for (int i = wave; i < 6; i += 4) {     // async-stage B (WowT)
            const ushort* src = WowT + (size_t)(i * 16 + lrow) * 256 + (k0 + lkk);
            async_load16(src, &Bsow[i * 16 * 32]);
        }
        __syncthreads();

        short8 af[2], bfw[3];
        #pragma unroll
        for (int i = 0; i < 2; ++i)
            af[i] = *(const short8*)&As[(wm * 32 + i * 16 + m16) * 32 + quad * 8];
        #pragma unroll
        for (int j = 0; j < 3; ++j)
            bfw[j] = *(const short8*)&Bsow[(wn * 48 + j * 16 + m16) * 32 + quad * 8];
        #pragma unroll
        for (int i = 0; i < 2; ++i)
            #pragma unroll
            for (int j = 0; j < 3; ++j)
                aow[i][j] = __builtin_amdgcn_mfma_f32_16x16x32_bf16(
                    af[i], bfw[j], aow[i][j], 0, 0, 0);
        __syncthreads();
    }
    // epilogue -> owl (f32), bias from boff|bw
    #pragma unroll
    for (int i = 0; i < 2; ++i)
        #pragma unroll
        for (int j = 0; j < 3; ++j) {
            const int col = wn * 48 + j * 16 + m16;
            const float bb = (col < 64) ? boff[col] : bw[col - 64];
            #pragma unroll
            for (int r = 0; r < 4; ++r)
                owl[(wm * 32 + i * 16 + quad * 4 + r) * 104 + col] = aow[i][j][r] + bb;
        }
    __syncthreads();

    // ---------------- phase 2: softmax + bilinear sampling ----------------
    {
        const int ql = tid >> 2;          // 0..63 query within block
        const int dg = tid & 3;           // channel group (8 ch)
        const int qg = q0 + ql;
        const int bb2 = qg >> 14;
        const float rx = ref[(size_t)qg * 2 + 0] * (float)GRID_W;
        const float ry = ref[(size_t)qg * 2 + 1] * (float)GRID_H;
        const ushort* vbase = v2 + (size_t)bb2 * 16384 * 256 + dg * 8;
        const float* owr = &owl[ql * 104];

        #pragma unroll 1
        for (int h = 0; h < 8; ++h) {
            const float w0 = owr[64 + h * 4 + 0], w1 = owr[64 + h * 4 + 1];
            const float w2 = owr[64 + h * 4 + 2], w3 = owr[64 + h * 4 + 3];
            const float mx = fmaxf(fmaxf(w0, w1), fmaxf(w2, w3));
            const float e0 = __expf(w0 - mx), e1 = __expf(w1 - mx);
            const float e2 = __expf(w2 - mx), e3 = __expf(w3 - mx);
            const float inv = 1.f / (e0 + e1 + e2 + e3);
            const float aw[4] = {e0 * inv, e1 * inv, e2 * inv, e3 * inv};

            const ushort* vh = vbase + h * 32;
            float acc8[8] = {};
            #pragma unroll
            for (int p = 0; p < 4; ++p) {
                const float x = rx + owr[h * 8 + p * 2 + 0] - 0.5f;
                const float y = ry + owr[h * 8 + p * 2 + 1] - 0.5f;
                const float x0f = floorf(x), y0f = floorf(y);
                const float dx = x - x0f, dy = y - y0f;
                const int x0 = (int)x0f, y0 = (int)y0f;
                const int x1 = x0 + 1, y1 = y0 + 1;
                const float vx0 = (x0 >= 0 && x0 < GRID_W) ? 1.f : 0.f;
                const float vx1 = (x1 >= 0 && x1 < GRID_W) ? 1.f : 0.f;
                const float vy0 = (y0 >= 0 && y0 < GRID_H) ? 1.f : 0.f;
                const float vy1 = (y1 >= 0 && y1 < GRID_H) ? 1.f : 0.f;
                const int xc0 = min(max(x0, 0), GRID_W - 1);
                const int xc1 = min(max(x1, 0), GRID_W - 1);
                const int yc0 = min(max(y0, 0), GRID_H - 1);
                const int yc1 = min(max(y1, 0), GRID_H - 1);
                const float cw00 = aw[p] * (1.f - dx) * (1.f - dy) * vx0 * vy0;
                const float cw10 = aw[p] * dx * (1.f - dy) * vx1 * vy0;
                const float cw01 = aw[p] * (1.f - dx) * dy * vx0 * vy1;
                const float cw11 = aw[p] * dx * dy * vx1 * vy1;
                const int base0 = yc0 * GRID_W, base1 = yc1 * GRID_W;
                const uint4 r00 = *(const uint4*)(vh + (size_t)(base0 + xc0) * 256);
                const uint4 r10 = *(const uint4*)(vh + (size_t)(base0 + xc1) * 256);
                const uint4 r01 = *(const uint4*)(vh + (size_t)(base1 + xc0) * 256);
                const uint4 r11 = *(const uint4*)(vh + (size_t)(base1 + xc1) * 256);
                float lo, hi;
                bf2x2(r00.x, lo, hi); acc8[0] += cw00 * lo; acc8[1] += cw00 * hi;
                bf2x2(r00.y, lo, hi); acc8[2] += cw00 * lo; acc8[3] += cw00 * hi;
                bf2x2(r00.z, lo, hi); acc8[4] += cw00 * lo; acc8[5] += cw00 * hi;
                bf2x2(r00.w, lo, hi); acc8[6] += cw00 * lo; acc8[7] += cw00 * hi;
                bf2x2(r10.x, lo, hi); acc8[0] += cw10 * lo; acc8[1] += cw10 * hi;
                bf2x2(r10.y, lo, hi); acc8[2] += cw10 * lo; acc8[3] += cw10 * hi;
                bf2x2(r10.z, lo, hi); acc8[4] += cw10 * lo; acc8[5] += cw10 * hi;
                bf2x2(r10.w, lo, hi); acc8[6] += cw10 * lo; acc8[7] += cw10 * hi;
                bf2x2(r01.x, lo, hi); acc8[0] += cw01 * lo; acc8[1] += cw01 * hi;
                bf2x2(r01.y, lo, hi); acc8[2] += cw01 * lo; acc8[3] += cw01 * hi;
                bf2x2(r01.z, lo, hi); acc8[4] += cw01 * lo; acc8[5] += cw01 * hi;
                bf2x2(r01.w, lo, hi); acc8[6] += cw01 * lo; acc8[7] += cw01 * hi;
                bf2x2(r11.x, lo, hi); acc8[0] += cw11 * lo; acc8[1] += cw11 * hi;
                bf2x2(r11.y, lo, hi); acc8[2] += cw11 * lo; acc8[3] += cw11 * hi;
                bf2x2(r11.z, lo, hi); acc8[4] += cw11 * lo; acc8[5] += cw11 * hi;
                bf2x2(r11.w, lo, hi); acc8[6] += cw11 * lo; acc8[7] += cw11 * hi;
            }
            uint4 o;
            o.x = ((uint32_t)f2bf(acc8[1]) << 16) | f2bf(acc8[0]);
            o.y = ((uint32_t)f2bf(acc8[3]) << 16) | f2bf(acc8[2]);
            o.z = ((uint32_t)f2bf(acc8[5]) << 16) | f2bf(acc8[4]);
            o.w = ((uint32_t)f2bf(acc8[7]) << 16) | f2bf(acc8[6]);
            *(uint4*)&samp[ql * 272 + h * 32 + dg * 8] = o;
        }
    }
    __syncthreads();   // samp ready; phase-1/ow LDS now dead -> reusable

    // ---------------- phase 3: out GEMM (double-buffered Wo staging) -----------
    auto stageW = [&](int buf, int ks) {
        for (int i = wave; i < 16; i += 4) {
            const ushort* src = WoT + (size_t)(i * 16 + lrow) * 256 + ks * 32 + lkk;
            async_load16(src, &Bwo[buf * 8192 + i * 16 * 32]);
        }
    };
    stageW(0, 0);
    __syncthreads();

    floatx4 acc[2][8] = {};
    int cur = 0;
    for (int ks = 0; ks < 8; ++ks) {
        if (ks + 1 < 8) stageW(cur ^ 1, ks + 1);

        short8 af[2], bfr[8];
        #pragma unroll
        for (int i = 0; i < 2; ++i)
            af[i] = *(const short8*)&samp[(wm * 32 + i * 16 + m16) * 272 + ks * 32 + quad * 8];
        #pragma unroll
        for (int j = 0; j < 8; ++j)
            bfr[j] = *(const short8*)&Bwo[cur * 8192 + (wn * 128 + j * 16 + m16) * 32 + quad * 8];
        #pragma unroll
        for (int i = 0; i < 2; ++i)
            #pragma unroll
            for (int j = 0; j < 8; ++j)
                acc[i][j] = __builtin_amdgcn_mfma_f32_16x16x32_bf16(
                    af[i], bfr[j], acc[i][j], 0, 0, 0);

        __syncthreads();
        cur ^= 1;
    }

    #pragma unroll
    for (int i = 0; i < 2; ++i)
        #pragma unroll
        for (int j = 0; j < 8; ++j) {
            const int gcol = wn * 128 + j * 16 + m16;
            const float bb = bo[gcol];
            #pragma unroll
            for (int r = 0; r < 4; ++r) {
                const int grow = q0 + wm * 32 + i * 16 + quad * 4 + r;
                out[(size_t)grow * 256 + gcol] =
                    acc[i][j][r] + bb + identity[(size_t)grow * 256 + gcol];
            }
        }
}

extern "C" void kernel_launch(void* const* d_in, const int* in_sizes, int n_in,
                              void* d_out, int out_size, void* d_ws, size_t ws_size,
                              hipStream_t stream) {
    const float* query     = (const float*)d_in[0];
    const float* value     = (const float*)d_in[1];
    const float* identity  = (const float*)d_in[2];
    const float* query_pos = (const float*)d_in[3];
    const float* refpts    = (const float*)d_in[4];
    const float* Wv   = (const float*)d_in[7];
    const float* bv   = (const float*)d_in[8];
    const float* Woff = (const float*)d_in[9];
    const float* boff = (const float*)d_in[10];
    const float* Ww   = (const float*)d_in[11];
    const float* bw   = (const float*)d_in[12];
    const float* Wo   = (const float*)d_in[13];
    const float* bo   = (const float*)d_in[14];
    float* out = (float*)d_out;

    char* ws = (char*)d_ws;
    ushort* v2_bf = (ushort*)(ws);                 // 16,777,216 B
    ushort* WvT   = (ushort*)(ws + 16777216);      //    131,072 B
    ushort* WoT   = (ushort*)(ws + 16908288);      //    131,072 B
    ushort* WowT  = (ushort*)(ws + 17039360);      //     49,152 B

    // 1) transposed bf16 weights
    prep_weights<<<608, 256, 0, stream>>>(Wv, Wo, Woff, Ww, WvT, WoT, WowT);
    // 2) v2 = value @ Wv + bv  (fp32 A converted in staging, bf16 out)
    gemm_bf16<128, 64, 2, 2, true, 1><<<dim3(4, 256), 256, 0, stream>>>(
        value, nullptr, WvT, bv, nullptr, v2_bf, Q_TOT, 256, 256);
    // 3) fused ow-GEMM + sampling + out-GEMM (+bo +identity)
    fused_attn<<<dim3(Q_TOT / FBM), 256, 0, stream>>>(
        query, query_pos, WowT, boff, bw, v2_bf, refpts, WoT, bo, identity, out);
}